// Round 5
// baseline (182.251 us; speedup 1.0000x reference)
//
#include <hip/hip_runtime.h>
#include <cstdint>

// ---------------------------------------------------------------------------
// CTC loss pipeline:
//   k_prep : x fp32->bf16, W[D,V] -> Wt[V,D] bf16, zero d_out
//   k_gemm : m97-structure bf16 MFMA GEMM, BK=64, 1-D grid with chunked-XCD
//            swizzle (n-major)
//   k_softmax_gather : row lse + ext-label exp-gather -> pext rows of 256
//            floats (s=0..255). State 256 (blank) == prow[0], no sidecar.
//   k_ctc  : 4 waves/block. Wave 0 runs the sequential scaled linear-domain
//            CTC scan; waves 1-3 are producers (each owns every 3rd chunk:
//            8x dwordx4 -> regs -> ds_write into 2-slot LDS ring, lgkmcnt(0),
//            raw s_barrier per chunk). Breaks the ~11 B/cy single-wave
//            streaming cap (R1 evidence: L3-warm == HBM-cold at 47 us).
// ---------------------------------------------------------------------------

#define PROW 256                      // pext row: 256 floats = 1 KiB
#define PEXT_PAD_ROWS 64              // prefetch overrun pad (loaded, never consumed)
#define L2E 1.4426950408889634f
#define LN2 0.6931471805599453f

typedef short v8s __attribute__((ext_vector_type(8)));
typedef float v4f __attribute__((ext_vector_type(4)));

__device__ __forceinline__ uint32_t f2bf_bits(float f) {
  uint32_t u = __float_as_uint(f);
  return (u + 0x7FFFu + ((u >> 16) & 1u)) >> 16;   // RNE
}
__device__ __forceinline__ float bf2f(uint32_t h) { return __uint_as_float(h << 16); }

// ---------------- k_prep: x fp32->bf16, W transpose->bf16, zero d_out ----------------
__global__ void k_prep(const float* __restrict__ x, uint16_t* __restrict__ xb, long long n,
                       const float* __restrict__ W, uint16_t* __restrict__ Wt, int D, int V,
                       float* __restrict__ out, int nconv) {
  if (blockIdx.x == 0 && threadIdx.x == 0) out[0] = 0.f;   // zero the atomic target
  if ((int)blockIdx.x < nconv) {
    long long i = ((long long)blockIdx.x * blockDim.x + threadIdx.x) * 8;
    if (i >= n) return;
    float4 a = *(const float4*)(x + i);
    float4 b = *(const float4*)(x + i + 4);
    uint4 o;
    o.x = f2bf_bits(a.x) | (f2bf_bits(a.y) << 16);
    o.y = f2bf_bits(a.z) | (f2bf_bits(a.w) << 16);
    o.z = f2bf_bits(b.x) | (f2bf_bits(b.y) << 16);
    o.w = f2bf_bits(b.z) | (f2bf_bits(b.w) << 16);
    *(uint4*)(xb + i) = o;
  } else {
    __shared__ float tile[32][33];
    const int bid2 = blockIdx.x - nconv;
    const int n0 = (bid2 % (V / 32)) * 32, k0 = (bid2 / (V / 32)) * 32;
    const int tx = threadIdx.x & 31, ty = threadIdx.x >> 5;   // (32,8)
    #pragma unroll
    for (int i = 0; i < 32; i += 8)
      tile[ty + i][tx] = W[(size_t)(k0 + ty + i) * V + n0 + tx];
    __syncthreads();
    #pragma unroll
    for (int i = 0; i < 32; i += 8)
      Wt[(size_t)(n0 + ty + i) * D + k0 + tx] = (uint16_t)f2bf_bits(tile[tx][ty + i]);
  }
}

// ---------------- k_gemm: m97 structure, BK=64, bf16 out, 1-D swizzled grid ----------------
__global__ __launch_bounds__(256) void k_gemm(const uint16_t* __restrict__ A,
                                              const uint16_t* __restrict__ Bt,
                                              const float* __restrict__ bias,
                                              uint16_t* __restrict__ C, int M, int N, int K) {
  __shared__ uint16_t As[2][128 * 32];   // [k-half][row*32 + k]  (64B rows)
  __shared__ uint16_t Bs[2][128 * 32];
  const int tid = threadIdx.x, lane = tid & 63, wave = tid >> 6;
  int d = blockIdx.x;
  const int nwg = gridDim.x;
  if ((nwg & 7) == 0) d = (d & 7) * (nwg >> 3) + (d >> 3);
  const int ntl = N >> 7;                       // N-tiles (n-major: fastest)
  const int m0 = (d / ntl) * 128, n0 = (d % ntl) * 128;
  const int wm = wave & 1, wn = wave >> 1;
  const int frow = lane & 15, kb = lane >> 4;
  const int lr = lane >> 2, kc = lane & 3;
  v4f acc[4][4] = {};

  for (int k0 = 0; k0 < K; k0 += 64) {
    __syncthreads();
    #pragma unroll
    for (int t = 0; t < 2; t++)
      #pragma unroll
      for (int i = 0; i < 2; i++) {
        const int r = (wave * 2 + i) * 16 + lr;
        const uint16_t* ga = A + (size_t)(m0 + r) * K + k0 + t * 32 + kc * 8;
        const uint16_t* gb = Bt + (size_t)(n0 + r) * K + k0 + t * 32 + kc * 8;
        __builtin_amdgcn_global_load_lds(
            (const __attribute__((address_space(1))) void*)ga,
            (__attribute__((address_space(3))) void*)(&As[t][0] + (wave * 2 + i) * 512 + lane * 8), 16, 0, 0);
        __builtin_amdgcn_global_load_lds(
            (const __attribute__((address_space(1))) void*)gb,
            (__attribute__((address_space(3))) void*)(&Bs[t][0] + (wave * 2 + i) * 512 + lane * 8), 16, 0, 0);
      }
    __syncthreads();

    #pragma unroll
    for (int t = 0; t < 2; t++) {
      v8s af[4], bf[4];
      #pragma unroll
      for (int i = 0; i < 4; i++)
        af[i] = *(const v8s*)(&As[t][0] + (wm * 64 + i * 16 + frow) * 32 + kb * 8);
      #pragma unroll
      for (int j = 0; j < 4; j++)
        bf[j] = *(const v8s*)(&Bs[t][0] + (wn * 64 + j * 16 + frow) * 32 + kb * 8);
      #pragma unroll
      for (int i = 0; i < 4; i++)
        #pragma unroll
        for (int j = 0; j < 4; j++)
          acc[i][j] = __builtin_amdgcn_mfma_f32_16x16x32_bf16(af[i], bf[j], acc[i][j], 0, 0, 0);
    }
  }

  const int crow = (lane >> 4) * 4, ccol = lane & 15;
  #pragma unroll
  for (int j = 0; j < 4; j++) {
    const int n = n0 + wn * 64 + j * 16 + ccol;
    const float bv = bias[n];
    #pragma unroll
    for (int i = 0; i < 4; i++) {
      const int mb = m0 + wm * 64 + i * 16 + crow;
      #pragma unroll
      for (int r2 = 0; r2 < 4; r2++)
        C[(size_t)(mb + r2) * N + n] = (uint16_t)f2bf_bits(acc[i][j][r2] + bv);
    }
  }
}

// ---------------- k_softmax_gather: row lse + gather (linear domain) ----------------
__global__ void k_softmax_gather(const uint16_t* __restrict__ logits, const int* __restrict__ target,
                                 const int* __restrict__ tlen, float* __restrict__ pext,
                                 int T, int V, int L) {
  const int row = blockIdx.x * 4 + (threadIdx.x >> 6);   // one wave per row
  const int lane = threadIdx.x & 63;
  const uint16_t* lrow = logits + (size_t)row * V;

  float xs[16];
  int cnt = 0;
  float mx = -INFINITY;
  for (int base = 0; base < V; base += 256) {
    const int idx = base + lane * 4;
    uint2 u = *(const uint2*)(lrow + idx);
    float4 v;
    v.x = bf2f(u.x & 0xFFFFu); v.y = bf2f(u.x >> 16);
    v.z = bf2f(u.y & 0xFFFFu); v.w = bf2f(u.y >> 16);
    xs[cnt] = v.x; xs[cnt + 1] = v.y; xs[cnt + 2] = v.z; xs[cnt + 3] = v.w; cnt += 4;
    mx = fmaxf(mx, fmaxf(fmaxf(v.x, v.y), fmaxf(v.z, v.w)));
  }
  #pragma unroll
  for (int off = 32; off; off >>= 1) mx = fmaxf(mx, __shfl_xor(mx, off, 64));
  float sum = 0.f;
  #pragma unroll
  for (int q = 0; q < 16; q++) { if (q < cnt) sum += exp2f((xs[q] - mx) * L2E); }
  #pragma unroll
  for (int off = 32; off; off >>= 1) sum += __shfl_xor(sum, off, 64);
  const float lse2 = mx * L2E + log2f(sum);

  const int bidx = row / T;
  const int Lb = tlen[bidx];
  const int S = 2 * Lb + 1;
  float* prow = pext + (size_t)row * PROW;
  #pragma unroll
  for (int it = 0; it < PROW / 64; it++) {
    const int s = lane + it * 64;
    float p = 0.f;
    if (s < S) {
      const int lbl = (s & 1) ? target[bidx * L + ((s - 1) >> 1)] : 0;
      p = exp2f(bf2f(lrow[lbl]) * L2E - lse2);
    }
    prow[s] = p;
  }
}

// ---------------- k_ctc: producer/consumer CTC forward, 4 waves per batch ----------------
__device__ __forceinline__ float wave_shr1(float x) {   // lane l <- lane l-1, lane0 <- 0
  return __int_as_float(__builtin_amdgcn_update_dpp(0, __float_as_int(x), 0x138, 0xf, 0xf, true));
}
__device__ __forceinline__ float wave_max_nonneg(float x) {
  x = fmaxf(x, __int_as_float(__builtin_amdgcn_update_dpp(0, __float_as_int(x), 0x111, 0xf, 0xf, true)));
  x = fmaxf(x, __int_as_float(__builtin_amdgcn_update_dpp(0, __float_as_int(x), 0x112, 0xf, 0xf, true)));
  x = fmaxf(x, __int_as_float(__builtin_amdgcn_update_dpp(0, __float_as_int(x), 0x114, 0xf, 0xf, true)));
  x = fmaxf(x, __int_as_float(__builtin_amdgcn_update_dpp(0, __float_as_int(x), 0x118, 0xf, 0xf, true)));
  x = fmaxf(x, __int_as_float(__builtin_amdgcn_update_dpp(0, __float_as_int(x), 0x142, 0xf, 0xf, true)));
  x = fmaxf(x, __int_as_float(__builtin_amdgcn_update_dpp(0, __float_as_int(x), 0x143, 0xf, 0xf, true)));
  return __int_as_float(__builtin_amdgcn_readlane(__float_as_int(x), 63));
}

__device__ __forceinline__ void load8r(float4* __restrict__ p,
                                       const float* __restrict__ pb, int t0, int lane) {
  #pragma unroll
  for (int k = 0; k < 8; k++)
    p[k] = *(const float4*)(pb + (size_t)(t0 + k) * PROW + (lane << 2));
}

__global__ __launch_bounds__(256, 1) void k_ctc(const float* __restrict__ pext,
                                                const int* __restrict__ target,
                                                const int* __restrict__ ilen,
                                                const int* __restrict__ tlen,
                                                float* __restrict__ out, int T, int L) {
  // Wave 0: sequential CTC scan (arithmetic identical to the R4 kernel).
  // Waves 1-3: producers. Producer p owns chunks c with c%3 == p-1.
  // During iteration c the owner of chunk c+1 ds_writes it into ring[(c+1)&1],
  // lgkmcnt(0), then issues plain-VGPR loads for its next chunk (c+4).
  // One raw s_barrier per iteration across all 4 waves; no vmcnt drains, so
  // producer loads stay in flight across barriers (3 iterations of cover).
  // 2-slot ring safety: writer slot (c+1)&1 != reader slot c&1; the reader's
  // ds_reads are consumed before its end-of-iteration barrier, and the slot
  // is only rewritten after that barrier.
  __shared__ __attribute__((aligned(16))) float ring[2][8][PROW];   // 16 KiB
  __shared__ float abuf[257];
  __shared__ float lc_sh;

  const int b = blockIdx.x;
  const int tid = threadIdx.x;
  const int lane = tid & 63, wave = tid >> 6;
  const int B = gridDim.x;
  const int Tb = ilen[b];
  const int Lb = tlen[b];
  const int S = 2 * Lb + 1;
  const int* tg = target + b * L;
  const float* pb = pext + (size_t)b * T * PROW;
  const int CT = (Tb + 6) >> 3;          // chunks of 8 steps covering t = 1..Tb-1

  if (wave == 0) {
    // ---------------- consumer ----------------
    const int s1 = 4 * lane + 1, s3 = 4 * lane + 3;
    float sk1 = 0.f, sk3 = 0.f;
    if (s1 >= 3 && s1 < S) sk1 = (tg[(s1 - 1) >> 1] != tg[(s1 - 3) >> 1]) ? 1.f : 0.f;
    if (s3 >= 3 && s3 < S) sk3 = (tg[(s3 - 1) >> 1] != tg[(s3 - 3) >> 1]) ? 1.f : 0.f;

    const float4 p0 = *(const float4*)(pb + (lane << 2));
    float a0 = (lane == 0) ? p0.x : 0.f;
    float a1 = (lane == 0) ? p0.y : 0.f;
    float a2 = 0.f, a3 = 0.f, a4 = 0.f;
    float log2C = 0.f;

    // State 256 is even -> blank -> equals prow[0] (lane 0's P.x): readlane.
    #define CTC_STEP(PP) {                                                \
      const float pm3 = wave_shr1(a3);                                    \
      const float a255 = __int_as_float(__builtin_amdgcn_readlane(__float_as_int(a3), 63)); \
      const float p4v = __int_as_float(__builtin_amdgcn_readlane(__float_as_int((PP).x), 0)); \
      const float n0v = (a0 + pm3) * (PP).x;                              \
      const float n1v = (a1 + a0 + sk1 * pm3) * (PP).y;                   \
      const float n2v = (a2 + a1) * (PP).z;                               \
      const float n3v = (a3 + a2 + sk3 * a1) * (PP).w;                    \
      const float n4v = (a4 + a255) * p4v;                                \
      a0 = n0v; a1 = n1v; a2 = n2v; a3 = n3v; a4 = n4v; }

    #define RENORM {                                                      \
      float m = fmaxf(fmaxf(fmaxf(a0, a1), fmaxf(a2, a3)), a4);           \
      m = wave_max_nonneg(m);                                             \
      const int e = (int)((__float_as_uint(m) >> 23) & 255u) - 127;       \
      const float scale = __uint_as_float((uint32_t)(127 - e) << 23);     \
      a0 *= scale; a1 *= scale; a2 *= scale; a3 *= scale; a4 *= scale;    \
      log2C += (float)e; }

    asm volatile("" ::: "memory");
    __builtin_amdgcn_s_barrier();          // prologue: chunk 0 published
    asm volatile("" ::: "memory");

    for (int c = 0; c < CT; ++c) {
      const int slot = c & 1;
      float4 P[8];
      #pragma unroll
      for (int k = 0; k < 8; ++k)
        P[k] = *(const float4*)(&ring[slot][k][lane << 2]);
      const int t0 = 1 + 8 * c;
      if (t0 + 8 <= Tb) {
        #pragma unroll
        for (int k = 0; k < 8; ++k) CTC_STEP(P[k]);
        RENORM;
      } else {
        #pragma unroll
        for (int k = 0; k < 8; ++k) { if (t0 + k < Tb) CTC_STEP(P[k]); }
        RENORM;
      }
      asm volatile("" ::: "memory");
      __builtin_amdgcn_s_barrier();
      asm volatile("" ::: "memory");
    }

    abuf[4 * lane + 0] = a0; abuf[4 * lane + 1] = a1;
    abuf[4 * lane + 2] = a2; abuf[4 * lane + 3] = a3;
    if (lane == 63) abuf[256] = a4;
    if (lane == 0) lc_sh = log2C;
  } else {
    // ---------------- producers (waves 1..3) ----------------
    const int p = wave;                     // 1..3
    float4 buf[8];
    const int c0 = p - 1;                   // first owned chunk
    if (c0 < CT) load8r(buf, pb, 1 + 8 * c0, lane);
    if (p == 1 && 0 < CT) {
      // publish chunk 0 now (compiler inserts the vmcnt wait for buf)
      #pragma unroll
      for (int k = 0; k < 8; ++k)
        *(float4*)(&ring[0][k][lane << 2]) = buf[k];
      if (3 < CT) load8r(buf, pb, 1 + 8 * 3, lane);   // next owned chunk
      asm volatile("s_waitcnt lgkmcnt(0)" ::: "memory");
    }
    asm volatile("" ::: "memory");
    __builtin_amdgcn_s_barrier();
    asm volatile("" ::: "memory");

    for (int c = 0; c < CT; ++c) {
      const int cpub = c + 1;
      if (cpub < CT && (cpub % 3) == p - 1) {
        const int slot = cpub & 1;
        #pragma unroll
        for (int k = 0; k < 8; ++k)
          *(float4*)(&ring[slot][k][lane << 2]) = buf[k];
        const int cnext = cpub + 3;
        if (cnext < CT) load8r(buf, pb, 1 + 8 * cnext, lane);
        asm volatile("s_waitcnt lgkmcnt(0)" ::: "memory");
      }
      asm volatile("" ::: "memory");
      __builtin_amdgcn_s_barrier();
      asm volatile("" ::: "memory");
    }
  }

  __syncthreads();
  if (tid == 0) {
    const float ssum = abuf[2 * Lb - 1] + abuf[2 * Lb];
    const float ll = (log2f(ssum) + lc_sh) * LN2;
    float nll = -ll;
    if (!(nll < 1e29f)) nll = 0.f;                 // zero_infinity (also catches inf/nan)
    atomicAdd(out, nll / ((float)(Lb > 0 ? Lb : 1) * (float)B));
  }
}

// ---------------------------------------------------------------------------
extern "C" void kernel_launch(void* const* d_in, const int* in_sizes, int n_in,
                              void* d_out, int out_size, void* d_ws, size_t ws_size,
                              hipStream_t stream) {
  const float* x      = (const float*)d_in[0];
  const float* W      = (const float*)d_in[1];
  const float* bias   = (const float*)d_in[2];
  const int*  target  = (const int*)d_in[3];
  const int*  ilen    = (const int*)d_in[4];
  const int*  tlen    = (const int*)d_in[5];

  const int B = in_sizes[4];
  const int V = in_sizes[2];
  const int D = in_sizes[1] / V;
  const int T = in_sizes[0] / (B * D);
  const int L = in_sizes[3] / B;
  const int M = B * T;

  char* ws = (char*)d_ws;
  const size_t xb_bytes = (size_t)M * D * 2;
  const size_t wt_bytes = (size_t)V * D * 2;
  uint16_t* xb = (uint16_t*)ws;
  uint16_t* Wt = (uint16_t*)(ws + xb_bytes);
  uint16_t* logits = (uint16_t*)(ws + xb_bytes + wt_bytes);
  const size_t log_bytes = (size_t)M * V * 2;

  const size_t pext_bytes = (size_t)(M + PEXT_PAD_ROWS) * PROW * 4;
  float* pext;
  if (pext_bytes <= xb_bytes + wt_bytes) {
    pext = (float*)ws;                 // overlay dead xb/Wt region after GEMM
  } else {
    pext = (float*)(ws + xb_bytes + wt_bytes + log_bytes);
  }

  const long long nx = (long long)M * D;
  const int nconv = (int)((nx / 8 + 255) / 256);
  const int ntrans = (V / 32) * (D / 32);
  k_prep<<<nconv + ntrans, 256, 0, stream>>>(x, xb, nx, W, Wt, D, V, (float*)d_out, nconv);
  k_gemm<<<(M / 128) * (V / 128), 256, 0, stream>>>(xb, Wt, bias, logits, M, V, D);
  k_softmax_gather<<<M / 4, 256, 0, stream>>>(logits, target, tlen, pext, T, V, L);
  k_ctc<<<B, 256, 0, stream>>>(pext, target, ilen, tlen, (float*)d_out, T, L);
}

// Round 7
// 156.828 us; speedup vs baseline: 1.1621x; 1.1621x over previous
//
#include <hip/hip_runtime.h>
#include <cstdint>

// ---------------------------------------------------------------------------
// CTC loss pipeline:
//   k_prep : x fp32->bf16, W[D,V] -> Wt[V,D] bf16, zero d_out
//   k_gemm : m97-structure bf16 MFMA GEMM, BK=64, 1-D grid with chunked-XCD
//            swizzle (n-major)
//   k_softmax_gather : row lse + ext-label exp-gather -> pext rows of 256
//            floats (s=0..255). State 256 (blank) == prow[0], no sidecar.
//   k_ctc  : 2 waves/block. Wave 0 = R4's proven 4-deep register-pipelined
//            sequential scan (8 dwordx4 ops/chunk). Wave 1 = L1 line-touch
//            prefetcher: 2 stride-64B dword ops per chunk at distance +4,
//            paced by one s_barrier per phase. Tests whether the ~95cy/op
//            per-wave VMEM service cap (R0/R1/R4 evidence) is an L1-miss-path
//            cost (helper converts consumer misses into L1 hits) at ~2 ops of
//            overhead. Consumer arithmetic bit-identical to R4.
// ---------------------------------------------------------------------------

#define PROW 256                      // pext row: 256 floats = 1 KiB
#define PEXT_PAD_ROWS 64              // prefetch overrun pad (loaded, never consumed)
#define L2E 1.4426950408889634f
#define LN2 0.6931471805599453f

typedef short v8s __attribute__((ext_vector_type(8)));
typedef float v4f __attribute__((ext_vector_type(4)));

__device__ __forceinline__ uint32_t f2bf_bits(float f) {
  uint32_t u = __float_as_uint(f);
  return (u + 0x7FFFu + ((u >> 16) & 1u)) >> 16;   // RNE
}
__device__ __forceinline__ float bf2f(uint32_t h) { return __uint_as_float(h << 16); }

// ---------------- k_prep: x fp32->bf16, W transpose->bf16, zero d_out ----------------
__global__ void k_prep(const float* __restrict__ x, uint16_t* __restrict__ xb, long long n,
                       const float* __restrict__ W, uint16_t* __restrict__ Wt, int D, int V,
                       float* __restrict__ out, int nconv) {
  if (blockIdx.x == 0 && threadIdx.x == 0) out[0] = 0.f;   // zero the atomic target
  if ((int)blockIdx.x < nconv) {
    long long i = ((long long)blockIdx.x * blockDim.x + threadIdx.x) * 8;
    if (i >= n) return;
    float4 a = *(const float4*)(x + i);
    float4 b = *(const float4*)(x + i + 4);
    uint4 o;
    o.x = f2bf_bits(a.x) | (f2bf_bits(a.y) << 16);
    o.y = f2bf_bits(a.z) | (f2bf_bits(a.w) << 16);
    o.z = f2bf_bits(b.x) | (f2bf_bits(b.y) << 16);
    o.w = f2bf_bits(b.z) | (f2bf_bits(b.w) << 16);
    *(uint4*)(xb + i) = o;
  } else {
    __shared__ float tile[32][33];
    const int bid2 = blockIdx.x - nconv;
    const int n0 = (bid2 % (V / 32)) * 32, k0 = (bid2 / (V / 32)) * 32;
    const int tx = threadIdx.x & 31, ty = threadIdx.x >> 5;   // (32,8)
    #pragma unroll
    for (int i = 0; i < 32; i += 8)
      tile[ty + i][tx] = W[(size_t)(k0 + ty + i) * V + n0 + tx];
    __syncthreads();
    #pragma unroll
    for (int i = 0; i < 32; i += 8)
      Wt[(size_t)(n0 + ty + i) * D + k0 + tx] = (uint16_t)f2bf_bits(tile[tx][ty + i]);
  }
}

// ---------------- k_gemm: m97 structure, BK=64, bf16 out, 1-D swizzled grid ----------------
__global__ __launch_bounds__(256) void k_gemm(const uint16_t* __restrict__ A,
                                              const uint16_t* __restrict__ Bt,
                                              const float* __restrict__ bias,
                                              uint16_t* __restrict__ C, int M, int N, int K) {
  __shared__ uint16_t As[2][128 * 32];   // [k-half][row*32 + k]  (64B rows)
  __shared__ uint16_t Bs[2][128 * 32];
  const int tid = threadIdx.x, lane = tid & 63, wave = tid >> 6;
  int d = blockIdx.x;
  const int nwg = gridDim.x;
  if ((nwg & 7) == 0) d = (d & 7) * (nwg >> 3) + (d >> 3);
  const int ntl = N >> 7;                       // N-tiles (n-major: fastest)
  const int m0 = (d / ntl) * 128, n0 = (d % ntl) * 128;
  const int wm = wave & 1, wn = wave >> 1;
  const int frow = lane & 15, kb = lane >> 4;
  const int lr = lane >> 2, kc = lane & 3;
  v4f acc[4][4] = {};

  for (int k0 = 0; k0 < K; k0 += 64) {
    __syncthreads();
    #pragma unroll
    for (int t = 0; t < 2; t++)
      #pragma unroll
      for (int i = 0; i < 2; i++) {
        const int r = (wave * 2 + i) * 16 + lr;
        const uint16_t* ga = A + (size_t)(m0 + r) * K + k0 + t * 32 + kc * 8;
        const uint16_t* gb = Bt + (size_t)(n0 + r) * K + k0 + t * 32 + kc * 8;
        __builtin_amdgcn_global_load_lds(
            (const __attribute__((address_space(1))) void*)ga,
            (__attribute__((address_space(3))) void*)(&As[t][0] + (wave * 2 + i) * 512 + lane * 8), 16, 0, 0);
        __builtin_amdgcn_global_load_lds(
            (const __attribute__((address_space(1))) void*)gb,
            (__attribute__((address_space(3))) void*)(&Bs[t][0] + (wave * 2 + i) * 512 + lane * 8), 16, 0, 0);
      }
    __syncthreads();

    #pragma unroll
    for (int t = 0; t < 2; t++) {
      v8s af[4], bf[4];
      #pragma unroll
      for (int i = 0; i < 4; i++)
        af[i] = *(const v8s*)(&As[t][0] + (wm * 64 + i * 16 + frow) * 32 + kb * 8);
      #pragma unroll
      for (int j = 0; j < 4; j++)
        bf[j] = *(const v8s*)(&Bs[t][0] + (wn * 64 + j * 16 + frow) * 32 + kb * 8);
      #pragma unroll
      for (int i = 0; i < 4; i++)
        #pragma unroll
        for (int j = 0; j < 4; j++)
          acc[i][j] = __builtin_amdgcn_mfma_f32_16x16x32_bf16(af[i], bf[j], acc[i][j], 0, 0, 0);
    }
  }

  const int crow = (lane >> 4) * 4, ccol = lane & 15;
  #pragma unroll
  for (int j = 0; j < 4; j++) {
    const int n = n0 + wn * 64 + j * 16 + ccol;
    const float bv = bias[n];
    #pragma unroll
    for (int i = 0; i < 4; i++) {
      const int mb = m0 + wm * 64 + i * 16 + crow;
      #pragma unroll
      for (int r2 = 0; r2 < 4; r2++)
        C[(size_t)(mb + r2) * N + n] = (uint16_t)f2bf_bits(acc[i][j][r2] + bv);
    }
  }
}

// ---------------- k_softmax_gather: row lse + gather (linear domain) ----------------
__global__ void k_softmax_gather(const uint16_t* __restrict__ logits, const int* __restrict__ target,
                                 const int* __restrict__ tlen, float* __restrict__ pext,
                                 int T, int V, int L) {
  const int row = blockIdx.x * 4 + (threadIdx.x >> 6);   // one wave per row
  const int lane = threadIdx.x & 63;
  const uint16_t* lrow = logits + (size_t)row * V;

  float xs[16];
  int cnt = 0;
  float mx = -INFINITY;
  for (int base = 0; base < V; base += 256) {
    const int idx = base + lane * 4;
    uint2 u = *(const uint2*)(lrow + idx);
    float4 v;
    v.x = bf2f(u.x & 0xFFFFu); v.y = bf2f(u.x >> 16);
    v.z = bf2f(u.y & 0xFFFFu); v.w = bf2f(u.y >> 16);
    xs[cnt] = v.x; xs[cnt + 1] = v.y; xs[cnt + 2] = v.z; xs[cnt + 3] = v.w; cnt += 4;
    mx = fmaxf(mx, fmaxf(fmaxf(v.x, v.y), fmaxf(v.z, v.w)));
  }
  #pragma unroll
  for (int off = 32; off; off >>= 1) mx = fmaxf(mx, __shfl_xor(mx, off, 64));
  float sum = 0.f;
  #pragma unroll
  for (int q = 0; q < 16; q++) { if (q < cnt) sum += exp2f((xs[q] - mx) * L2E); }
  #pragma unroll
  for (int off = 32; off; off >>= 1) sum += __shfl_xor(sum, off, 64);
  const float lse2 = mx * L2E + log2f(sum);

  const int bidx = row / T;
  const int Lb = tlen[bidx];
  const int S = 2 * Lb + 1;
  float* prow = pext + (size_t)row * PROW;
  #pragma unroll
  for (int it = 0; it < PROW / 64; it++) {
    const int s = lane + it * 64;
    float p = 0.f;
    if (s < S) {
      const int lbl = (s & 1) ? target[bidx * L + ((s - 1) >> 1)] : 0;
      p = exp2f(bf2f(lrow[lbl]) * L2E - lse2);
    }
    prow[s] = p;
  }
}

// ---------------- k_ctc: R4 scan (wave 0) + L1 line-touch helper (wave 1) ----------------
__device__ __forceinline__ float wave_shr1(float x) {   // lane l <- lane l-1, lane0 <- 0
  return __int_as_float(__builtin_amdgcn_update_dpp(0, __float_as_int(x), 0x138, 0xf, 0xf, true));
}
__device__ __forceinline__ float wave_max_nonneg(float x) {
  x = fmaxf(x, __int_as_float(__builtin_amdgcn_update_dpp(0, __float_as_int(x), 0x111, 0xf, 0xf, true)));
  x = fmaxf(x, __int_as_float(__builtin_amdgcn_update_dpp(0, __float_as_int(x), 0x112, 0xf, 0xf, true)));
  x = fmaxf(x, __int_as_float(__builtin_amdgcn_update_dpp(0, __float_as_int(x), 0x114, 0xf, 0xf, true)));
  x = fmaxf(x, __int_as_float(__builtin_amdgcn_update_dpp(0, __float_as_int(x), 0x118, 0xf, 0xf, true)));
  x = fmaxf(x, __int_as_float(__builtin_amdgcn_update_dpp(0, __float_as_int(x), 0x142, 0xf, 0xf, true)));
  x = fmaxf(x, __int_as_float(__builtin_amdgcn_update_dpp(0, __float_as_int(x), 0x143, 0xf, 0xf, true)));
  return __int_as_float(__builtin_amdgcn_readlane(__float_as_int(x), 63));
}

// 8-row chunk load: pure float4 loads, 8 VMEM ops total (the minimum for 8 KiB).
__device__ __forceinline__ void load8(float4* __restrict__ p,
                                      const float* __restrict__ pb, int t0, int lane) {
  #pragma unroll
  for (int k = 0; k < 8; k++)
    p[k] = *(const float4*)(pb + (size_t)(t0 + k) * PROW + (lane << 2));
}

__global__ __launch_bounds__(128, 1) void k_ctc(const float* __restrict__ pext,
                                                const int* __restrict__ target,
                                                const int* __restrict__ ilen,
                                                const int* __restrict__ tlen,
                                                float* __restrict__ out, int T, int L) {
  const int b = blockIdx.x;
  const int tid = threadIdx.x;
  const int lane = tid & 63, wave = tid >> 6;
  const int B = gridDim.x;
  const int Tb = ilen[b];
  const int Lb = tlen[b];
  const int S = 2 * Lb + 1;
  const int* tg = target + b * L;
  const float* pb = pext + (size_t)b * T * PROW;
  // Phase count of the consumer's while-loop below, for ALL Tb >= 1:
  //   full phases while t0+8 <= Tb (t0 = 1+8c), then exactly one tail phase.
  //   => CT = (Tb-1)/8 + 1.  (Tb=512 -> 64; verified for Tb=1,8,9,16,17.)
  const int CT = (Tb - 1) / 8 + 1;

  if (wave == 1) {
    // --------- L1 line-touch prefetcher: 2 dword ops per chunk, distance +4.
    // One dword per 64B line pulls the full line into the CU's L1 (32 KiB =
    // 4 chunks; working set here is 2 chunks). Barrier-paced to stay exactly
    // 1 phase ahead of the consumer's own chunk-(c+3) prefetch loads.
    {  // best-effort prologue touch of chunk 3 (consumer loads it at phase 0)
      const float* src = pb + (size_t)(1 + 8 * 3) * PROW;
      float u0 = src[lane * 16];
      float u1 = src[1024 + lane * 16];
      asm volatile("" :: "v"(u0), "v"(u1));
    }
    for (int c = 0; c < CT; ++c) {
      if (c + 4 < CT) {
        const float* src = pb + (size_t)(1 + 8 * (c + 4)) * PROW;   // 8 KiB chunk
        float u0 = src[lane * 16];          // lines 0..63   (byte l*64)
        float u1 = src[1024 + lane * 16];   // lines 64..127
        asm volatile("" :: "v"(u0), "v"(u1));
      }
      __builtin_amdgcn_s_barrier();
    }
    return;
  }

  // ---------------- wave 0: consumer (bit-identical arithmetic to R4) ----------------
  const int s1 = 4 * lane + 1, s3 = 4 * lane + 3;
  float sk1 = 0.f, sk3 = 0.f;
  if (s1 >= 3 && s1 < S) sk1 = (tg[(s1 - 1) >> 1] != tg[(s1 - 3) >> 1]) ? 1.f : 0.f;
  if (s3 >= 3 && s3 < S) sk3 = (tg[(s3 - 1) >> 1] != tg[(s3 - 3) >> 1]) ? 1.f : 0.f;

  const float4 p0 = *(const float4*)(pb + (lane << 2));
  float a0 = (lane == 0) ? p0.x : 0.f;
  float a1 = (lane == 0) ? p0.y : 0.f;
  float a2 = 0.f, a3 = 0.f, a4 = 0.f;
  float log2C = 0.f;

  // State 256 is even -> blank -> equals prow[0] (lane 0's P.x): readlane.
  #define CTC_STEP(PP) {                                                \
    const float pm3 = wave_shr1(a3);                                    \
    const float a255 = __int_as_float(__builtin_amdgcn_readlane(__float_as_int(a3), 63)); \
    const float p4v = __int_as_float(__builtin_amdgcn_readlane(__float_as_int((PP).x), 0)); \
    const float n0v = (a0 + pm3) * (PP).x;                              \
    const float n1v = (a1 + a0 + sk1 * pm3) * (PP).y;                   \
    const float n2v = (a2 + a1) * (PP).z;                               \
    const float n3v = (a3 + a2 + sk3 * a1) * (PP).w;                    \
    const float n4v = (a4 + a255) * p4v;                                \
    a0 = n0v; a1 = n1v; a2 = n2v; a3 = n3v; a4 = n4v; }

  #define RENORM {                                                      \
    float m = fmaxf(fmaxf(fmaxf(a0, a1), fmaxf(a2, a3)), a4);           \
    m = wave_max_nonneg(m);                                             \
    const int e = (int)((__float_as_uint(m) >> 23) & 255u) - 127;       \
    const float scale = __uint_as_float((uint32_t)(127 - e) << 23);     \
    a0 *= scale; a1 *= scale; a2 *= scale; a3 *= scale; a4 *= scale;    \
    log2C += (float)e; }

  // 4-stage software pipeline, 8-row chunks, prefetch distance = 3 chunks.
  // sched_barrier(0) after each load block pins the loads ABOVE the compute.
  // One s_barrier per phase paces the helper wave (no data exchanged).
  float4 Pa[8], Pb_[8], Pc[8], Pd[8];
  int t0 = 1;
  bool done = false;
  load8(Pa, pb, t0, lane);
  load8(Pb_, pb, t0 + 8, lane);
  load8(Pc, pb, t0 + 16, lane);
  __builtin_amdgcn_sched_barrier(0);

  #define PHASE(LP, CP) {                                               \
    if (t0 + 8 <= Tb) {                                                 \
      load8(LP, pb, t0 + 24, lane);                                     \
      __builtin_amdgcn_sched_barrier(0);                                \
      _Pragma("unroll")                                                 \
      for (int k = 0; k < 8; k++) CTC_STEP(CP[k]);                      \
      RENORM; t0 += 8;                                                  \
    } else {                                                            \
      _Pragma("unroll")                                                 \
      for (int k = 0; k < 8; k++) { if (t0 + k < Tb) CTC_STEP(CP[k]); } \
      RENORM; done = true;                                              \
    }                                                                   \
    __builtin_amdgcn_s_barrier(); }

  while (!done) {
    PHASE(Pd, Pa); if (done) break;
    PHASE(Pa, Pb_); if (done) break;
    PHASE(Pb_, Pc); if (done) break;
    PHASE(Pc, Pd);
  }

  __shared__ float abuf[257];
  abuf[4 * lane + 0] = a0; abuf[4 * lane + 1] = a1;
  abuf[4 * lane + 2] = a2; abuf[4 * lane + 3] = a3;
  if (lane == 63) abuf[256] = a4;
  // abuf is written and read by wave 0 only (in-wave DS ordering suffices).
  if (lane == 0) {
    const float ssum = abuf[2 * Lb - 1] + abuf[2 * Lb];
    const float ll = (log2f(ssum) + log2C) * LN2;
    float nll = -ll;
    if (!(nll < 1e29f)) nll = 0.f;                 // zero_infinity (also catches inf/nan)
    atomicAdd(out, nll / ((float)(Lb > 0 ? Lb : 1) * (float)B));
  }
}

// ---------------------------------------------------------------------------
extern "C" void kernel_launch(void* const* d_in, const int* in_sizes, int n_in,
                              void* d_out, int out_size, void* d_ws, size_t ws_size,
                              hipStream_t stream) {
  const float* x      = (const float*)d_in[0];
  const float* W      = (const float*)d_in[1];
  const float* bias   = (const float*)d_in[2];
  const int*  target  = (const int*)d_in[3];
  const int*  ilen    = (const int*)d_in[4];
  const int*  tlen    = (const int*)d_in[5];

  const int B = in_sizes[4];
  const int V = in_sizes[2];
  const int D = in_sizes[1] / V;
  const int T = in_sizes[0] / (B * D);
  const int L = in_sizes[3] / B;
  const int M = B * T;

  char* ws = (char*)d_ws;
  const size_t xb_bytes = (size_t)M * D * 2;
  const size_t wt_bytes = (size_t)V * D * 2;
  uint16_t* xb = (uint16_t*)ws;
  uint16_t* Wt = (uint16_t*)(ws + xb_bytes);
  uint16_t* logits = (uint16_t*)(ws + xb_bytes + wt_bytes);
  const size_t log_bytes = (size_t)M * V * 2;

  const size_t pext_bytes = (size_t)(M + PEXT_PAD_ROWS) * PROW * 4;
  float* pext;
  if (pext_bytes <= xb_bytes + wt_bytes) {
    pext = (float*)ws;                 // overlay dead xb/Wt region after GEMM
  } else {
    pext = (float*)(ws + xb_bytes + wt_bytes + log_bytes);
  }

  const long long nx = (long long)M * D;
  const int nconv = (int)((nx / 8 + 255) / 256);
  const int ntrans = (V / 32) * (D / 32);
  k_prep<<<nconv + ntrans, 256, 0, stream>>>(x, xb, nx, W, Wt, D, V, (float*)d_out, nconv);
  k_gemm<<<(M / 128) * (V / 128), 256, 0, stream>>>(xb, Wt, bias, logits, M, V, D);
  k_softmax_gather<<<M / 4, 256, 0, stream>>>(logits, target, tlen, pext, T, V, L);
  k_ctc<<<B, 128, 0, stream>>>(pext, target, ilen, tlen, (float*)d_out, T, L);
}

// Round 8
// 156.260 us; speedup vs baseline: 1.1663x; 1.0036x over previous
//
#include <hip/hip_runtime.h>
#include <cstdint>

// ---------------------------------------------------------------------------
// CTC loss pipeline:
//   k_prep : x fp32->bf16, W[D,V] -> Wt[V,D] bf16, zero d_out
//   k_gemm : m97-structure bf16 MFMA GEMM, BK=64, 1-D grid with chunked-XCD
//            swizzle (n-major)
//   k_softmax_gather : row lse + ext-label exp-gather -> pext rows of 256
//            floats (s=0..255). State 256 (blank) == prow[0], no sidecar.
//   k_ctc  : producer/consumer v2. Wave 0 = sequential CTC scan reading 8 KiB
//            chunks from an LDS ring via ds_read_b128 (~12cy/op vs ~95cy/op
//            for per-wave VMEM — R1/R4/R7 evidence: the per-op cost is the
//            wave's 16-line address fan-out, paid at EVERY hit tier).
//            Waves 1-6 = producers, chunk c owned by wave 1+(c%6):
//            named-reg P0..P7 (R5's VGPR=32 spill designed out), batched
//            ds_write_b128 publish, reload AFTER publish (sched_barrier
//            pinned), lgkmcnt(0)+s_barrier per phase, vmcnt never drained.
// ---------------------------------------------------------------------------

#define PROW 256                      // pext row: 256 floats = 1 KiB
#define PEXT_PAD_ROWS 64              // prefetch overrun pad (loaded, never consumed)
#define NPROD 6                       // producer waves
#define NSLOT 4                       // LDS ring slots (8 KiB each)
#define L2E 1.4426950408889634f
#define LN2 0.6931471805599453f

typedef short v8s __attribute__((ext_vector_type(8)));
typedef float v4f __attribute__((ext_vector_type(4)));

__device__ __forceinline__ uint32_t f2bf_bits(float f) {
  uint32_t u = __float_as_uint(f);
  return (u + 0x7FFFu + ((u >> 16) & 1u)) >> 16;   // RNE
}
__device__ __forceinline__ float bf2f(uint32_t h) { return __uint_as_float(h << 16); }

// ---------------- k_prep: x fp32->bf16, W transpose->bf16, zero d_out ----------------
__global__ void k_prep(const float* __restrict__ x, uint16_t* __restrict__ xb, long long n,
                       const float* __restrict__ W, uint16_t* __restrict__ Wt, int D, int V,
                       float* __restrict__ out, int nconv) {
  if (blockIdx.x == 0 && threadIdx.x == 0) out[0] = 0.f;   // zero the atomic target
  if ((int)blockIdx.x < nconv) {
    long long i = ((long long)blockIdx.x * blockDim.x + threadIdx.x) * 8;
    if (i >= n) return;
    float4 a = *(const float4*)(x + i);
    float4 b = *(const float4*)(x + i + 4);
    uint4 o;
    o.x = f2bf_bits(a.x) | (f2bf_bits(a.y) << 16);
    o.y = f2bf_bits(a.z) | (f2bf_bits(a.w) << 16);
    o.z = f2bf_bits(b.x) | (f2bf_bits(b.y) << 16);
    o.w = f2bf_bits(b.z) | (f2bf_bits(b.w) << 16);
    *(uint4*)(xb + i) = o;
  } else {
    __shared__ float tile[32][33];
    const int bid2 = blockIdx.x - nconv;
    const int n0 = (bid2 % (V / 32)) * 32, k0 = (bid2 / (V / 32)) * 32;
    const int tx = threadIdx.x & 31, ty = threadIdx.x >> 5;   // (32,8)
    #pragma unroll
    for (int i = 0; i < 32; i += 8)
      tile[ty + i][tx] = W[(size_t)(k0 + ty + i) * V + n0 + tx];
    __syncthreads();
    #pragma unroll
    for (int i = 0; i < 32; i += 8)
      Wt[(size_t)(n0 + ty + i) * D + k0 + tx] = (uint16_t)f2bf_bits(tile[tx][ty + i]);
  }
}

// ---------------- k_gemm: m97 structure, BK=64, bf16 out, 1-D swizzled grid ----------------
__global__ __launch_bounds__(256) void k_gemm(const uint16_t* __restrict__ A,
                                              const uint16_t* __restrict__ Bt,
                                              const float* __restrict__ bias,
                                              uint16_t* __restrict__ C, int M, int N, int K) {
  __shared__ uint16_t As[2][128 * 32];   // [k-half][row*32 + k]  (64B rows)
  __shared__ uint16_t Bs[2][128 * 32];
  const int tid = threadIdx.x, lane = tid & 63, wave = tid >> 6;
  int d = blockIdx.x;
  const int nwg = gridDim.x;
  if ((nwg & 7) == 0) d = (d & 7) * (nwg >> 3) + (d >> 3);
  const int ntl = N >> 7;                       // N-tiles (n-major: fastest)
  const int m0 = (d / ntl) * 128, n0 = (d % ntl) * 128;
  const int wm = wave & 1, wn = wave >> 1;
  const int frow = lane & 15, kb = lane >> 4;
  const int lr = lane >> 2, kc = lane & 3;
  v4f acc[4][4] = {};

  for (int k0 = 0; k0 < K; k0 += 64) {
    __syncthreads();
    #pragma unroll
    for (int t = 0; t < 2; t++)
      #pragma unroll
      for (int i = 0; i < 2; i++) {
        const int r = (wave * 2 + i) * 16 + lr;
        const uint16_t* ga = A + (size_t)(m0 + r) * K + k0 + t * 32 + kc * 8;
        const uint16_t* gb = Bt + (size_t)(n0 + r) * K + k0 + t * 32 + kc * 8;
        __builtin_amdgcn_global_load_lds(
            (const __attribute__((address_space(1))) void*)ga,
            (__attribute__((address_space(3))) void*)(&As[t][0] + (wave * 2 + i) * 512 + lane * 8), 16, 0, 0);
        __builtin_amdgcn_global_load_lds(
            (const __attribute__((address_space(1))) void*)gb,
            (__attribute__((address_space(3))) void*)(&Bs[t][0] + (wave * 2 + i) * 512 + lane * 8), 16, 0, 0);
      }
    __syncthreads();

    #pragma unroll
    for (int t = 0; t < 2; t++) {
      v8s af[4], bf[4];
      #pragma unroll
      for (int i = 0; i < 4; i++)
        af[i] = *(const v8s*)(&As[t][0] + (wm * 64 + i * 16 + frow) * 32 + kb * 8);
      #pragma unroll
      for (int j = 0; j < 4; j++)
        bf[j] = *(const v8s*)(&Bs[t][0] + (wn * 64 + j * 16 + frow) * 32 + kb * 8);
      #pragma unroll
      for (int i = 0; i < 4; i++)
        #pragma unroll
        for (int j = 0; j < 4; j++)
          acc[i][j] = __builtin_amdgcn_mfma_f32_16x16x32_bf16(af[i], bf[j], acc[i][j], 0, 0, 0);
    }
  }

  const int crow = (lane >> 4) * 4, ccol = lane & 15;
  #pragma unroll
  for (int j = 0; j < 4; j++) {
    const int n = n0 + wn * 64 + j * 16 + ccol;
    const float bv = bias[n];
    #pragma unroll
    for (int i = 0; i < 4; i++) {
      const int mb = m0 + wm * 64 + i * 16 + crow;
      #pragma unroll
      for (int r2 = 0; r2 < 4; r2++)
        C[(size_t)(mb + r2) * N + n] = (uint16_t)f2bf_bits(acc[i][j][r2] + bv);
    }
  }
}

// ---------------- k_softmax_gather: row lse + gather (linear domain) ----------------
__global__ void k_softmax_gather(const uint16_t* __restrict__ logits, const int* __restrict__ target,
                                 const int* __restrict__ tlen, float* __restrict__ pext,
                                 int T, int V, int L) {
  const int row = blockIdx.x * 4 + (threadIdx.x >> 6);   // one wave per row
  const int lane = threadIdx.x & 63;
  const uint16_t* lrow = logits + (size_t)row * V;

  float xs[16];
  int cnt = 0;
  float mx = -INFINITY;
  for (int base = 0; base < V; base += 256) {
    const int idx = base + lane * 4;
    uint2 u = *(const uint2*)(lrow + idx);
    float4 v;
    v.x = bf2f(u.x & 0xFFFFu); v.y = bf2f(u.x >> 16);
    v.z = bf2f(u.y & 0xFFFFu); v.w = bf2f(u.y >> 16);
    xs[cnt] = v.x; xs[cnt + 1] = v.y; xs[cnt + 2] = v.z; xs[cnt + 3] = v.w; cnt += 4;
    mx = fmaxf(mx, fmaxf(fmaxf(v.x, v.y), fmaxf(v.z, v.w)));
  }
  #pragma unroll
  for (int off = 32; off; off >>= 1) mx = fmaxf(mx, __shfl_xor(mx, off, 64));
  float sum = 0.f;
  #pragma unroll
  for (int q = 0; q < 16; q++) { if (q < cnt) sum += exp2f((xs[q] - mx) * L2E); }
  #pragma unroll
  for (int off = 32; off; off >>= 1) sum += __shfl_xor(sum, off, 64);
  const float lse2 = mx * L2E + log2f(sum);

  const int bidx = row / T;
  const int Lb = tlen[bidx];
  const int S = 2 * Lb + 1;
  float* prow = pext + (size_t)row * PROW;
  #pragma unroll
  for (int it = 0; it < PROW / 64; it++) {
    const int s = lane + it * 64;
    float p = 0.f;
    if (s < S) {
      const int lbl = (s & 1) ? target[bidx * L + ((s - 1) >> 1)] : 0;
      p = exp2f(bf2f(lrow[lbl]) * L2E - lse2);
    }
    prow[s] = p;
  }
}

// ---------------- k_ctc: producer/consumer v2, 7 waves per batch ----------------
__device__ __forceinline__ float wave_shr1(float x) {   // lane l <- lane l-1, lane0 <- 0
  return __int_as_float(__builtin_amdgcn_update_dpp(0, __float_as_int(x), 0x138, 0xf, 0xf, true));
}
__device__ __forceinline__ float wave_max_nonneg(float x) {
  x = fmaxf(x, __int_as_float(__builtin_amdgcn_update_dpp(0, __float_as_int(x), 0x111, 0xf, 0xf, true)));
  x = fmaxf(x, __int_as_float(__builtin_amdgcn_update_dpp(0, __float_as_int(x), 0x112, 0xf, 0xf, true)));
  x = fmaxf(x, __int_as_float(__builtin_amdgcn_update_dpp(0, __float_as_int(x), 0x114, 0xf, 0xf, true)));
  x = fmaxf(x, __int_as_float(__builtin_amdgcn_update_dpp(0, __float_as_int(x), 0x118, 0xf, 0xf, true)));
  x = fmaxf(x, __int_as_float(__builtin_amdgcn_update_dpp(0, __float_as_int(x), 0x142, 0xf, 0xf, true)));
  x = fmaxf(x, __int_as_float(__builtin_amdgcn_update_dpp(0, __float_as_int(x), 0x143, 0xf, 0xf, true)));
  return __int_as_float(__builtin_amdgcn_readlane(__float_as_int(x), 63));
}

__global__ __launch_bounds__(448, 1) void k_ctc(const float* __restrict__ pext,
                                                const int* __restrict__ target,
                                                const int* __restrict__ ilen,
                                                const int* __restrict__ tlen,
                                                float* __restrict__ out, int T, int L) {
  __shared__ __attribute__((aligned(16))) float ring[NSLOT][8][PROW];   // 32 KiB
  __shared__ float abuf[257];

  const int b = blockIdx.x;
  const int tid = threadIdx.x;
  const int lane = tid & 63, wave = tid >> 6;
  const int B = gridDim.x;
  const int Tb = ilen[b];
  const int Lb = tlen[b];
  const int S = 2 * Lb + 1;
  const int* tg = target + b * L;
  const float* pb = pext + (size_t)b * T * PROW;
  // Phase structure: CT = (Tb-1)/8 + 1 phases; phases 0..CT-2 are full (8
  // steps), phase CT-1 is the tail (reproduces R4's while-loop exactly).
  // Every wave executes exactly CT+1 s_barriers (1 prologue + 1 per phase).
  const int CT = (Tb - 1) / 8 + 1;

  if (wave > 0) {
    // ---------------- producers (waves 1..NPROD) ----------------
    const int p = wave - 1;              // owns chunks c with c % NPROD == p
    float4 P0, P1, P2, P3, P4, P5, P6, P7;   // named regs: no spill (R5 lesson)

    #define LOADCHUNK(c) {                                                  \
      const float* s_ = pb + (size_t)(1 + 8 * (c)) * PROW + (lane << 2);    \
      P0 = *(const float4*)(s_);            P1 = *(const float4*)(s_ + PROW);     \
      P2 = *(const float4*)(s_ + 2 * PROW); P3 = *(const float4*)(s_ + 3 * PROW); \
      P4 = *(const float4*)(s_ + 4 * PROW); P5 = *(const float4*)(s_ + 5 * PROW); \
      P6 = *(const float4*)(s_ + 6 * PROW); P7 = *(const float4*)(s_ + 7 * PROW); }
    #define WRITECHUNK(c) {                                                 \
      const int sl_ = (c) & (NSLOT - 1);                                    \
      *(float4*)(&ring[sl_][0][lane << 2]) = P0; *(float4*)(&ring[sl_][1][lane << 2]) = P1; \
      *(float4*)(&ring[sl_][2][lane << 2]) = P2; *(float4*)(&ring[sl_][3][lane << 2]) = P3; \
      *(float4*)(&ring[sl_][4][lane << 2]) = P4; *(float4*)(&ring[sl_][5][lane << 2]) = P5; \
      *(float4*)(&ring[sl_][6][lane << 2]) = P6; *(float4*)(&ring[sl_][7][lane << 2]) = P7; }

    if (p < CT) LOADCHUNK(p);            // first owned chunk
    if (p == 0) {                        // publish chunk 0 in the prologue
      WRITECHUNK(0);
      __builtin_amdgcn_sched_barrier(0);
      if (NPROD < CT) LOADCHUNK(NPROD);  // refill with next owned chunk
      __builtin_amdgcn_sched_barrier(0);
      asm volatile("s_waitcnt lgkmcnt(0)" ::: "memory");
    }
    __builtin_amdgcn_s_barrier();        // prologue barrier

    for (int c = 0; c < CT; ++c) {
      const int cpub = c + 1;            // chunk consumed at phase c+1
      if (cpub < CT && (cpub % NPROD) == p) {
        // regs hold chunk cpub (loaded NPROD phases ago -> vmcnt wait is free)
        WRITECHUNK(cpub);
        __builtin_amdgcn_sched_barrier(0);
        const int cn = cpub + NPROD;
        if (cn < CT) LOADCHUNK(cn);      // reload AFTER publish; stays in flight
        __builtin_amdgcn_sched_barrier(0);
        asm volatile("s_waitcnt lgkmcnt(0)" ::: "memory");   // writes land pre-barrier
      }
      __builtin_amdgcn_s_barrier();
    }
    return;
  }

  // ---------------- wave 0: consumer (bit-identical arithmetic to R4) ----------------
  const int s1 = 4 * lane + 1, s3 = 4 * lane + 3;
  float sk1 = 0.f, sk3 = 0.f;
  if (s1 >= 3 && s1 < S) sk1 = (tg[(s1 - 1) >> 1] != tg[(s1 - 3) >> 1]) ? 1.f : 0.f;
  if (s3 >= 3 && s3 < S) sk3 = (tg[(s3 - 1) >> 1] != tg[(s3 - 3) >> 1]) ? 1.f : 0.f;

  const float4 p0 = *(const float4*)(pb + (lane << 2));
  float a0 = (lane == 0) ? p0.x : 0.f;
  float a1 = (lane == 0) ? p0.y : 0.f;
  float a2 = 0.f, a3 = 0.f, a4 = 0.f;
  float log2C = 0.f;

  // State 256 is even -> blank -> equals prow[0] (lane 0's P.x): readlane.
  #define CTC_STEP(PP) {                                                \
    const float pm3 = wave_shr1(a3);                                    \
    const float a255 = __int_as_float(__builtin_amdgcn_readlane(__float_as_int(a3), 63)); \
    const float p4v = __int_as_float(__builtin_amdgcn_readlane(__float_as_int((PP).x), 0)); \
    const float n0v = (a0 + pm3) * (PP).x;                              \
    const float n1v = (a1 + a0 + sk1 * pm3) * (PP).y;                   \
    const float n2v = (a2 + a1) * (PP).z;                               \
    const float n3v = (a3 + a2 + sk3 * a1) * (PP).w;                    \
    const float n4v = (a4 + a255) * p4v;                                \
    a0 = n0v; a1 = n1v; a2 = n2v; a3 = n3v; a4 = n4v; }

  #define RENORM {                                                      \
    float m = fmaxf(fmaxf(fmaxf(a0, a1), fmaxf(a2, a3)), a4);           \
    m = wave_max_nonneg(m);                                             \
    const int e = (int)((__float_as_uint(m) >> 23) & 255u) - 127;       \
    const float scale = __uint_as_float((uint32_t)(127 - e) << 23);     \
    a0 *= scale; a1 *= scale; a2 *= scale; a3 *= scale; a4 *= scale;    \
    log2C += (float)e; }

  __builtin_amdgcn_s_barrier();          // prologue barrier (chunk 0 published)

  for (int c = 0; c < CT; ++c) {
    const int slot = c & (NSLOT - 1);
    float4 P[8];
    #pragma unroll
    for (int k = 0; k < 8; ++k)
      P[k] = *(const float4*)(&ring[slot][k][lane << 2]);
    const int t0 = 1 + 8 * c;
    if (t0 + 8 <= Tb) {
      #pragma unroll
      for (int k = 0; k < 8; ++k) CTC_STEP(P[k]);
      RENORM;
    } else {
      #pragma unroll
      for (int k = 0; k < 8; ++k) { if (t0 + k < Tb) CTC_STEP(P[k]); }
      RENORM;
    }
    __builtin_amdgcn_s_barrier();
  }

  abuf[4 * lane + 0] = a0; abuf[4 * lane + 1] = a1;
  abuf[4 * lane + 2] = a2; abuf[4 * lane + 3] = a3;
  if (lane == 63) abuf[256] = a4;
  // abuf is written and read by wave 0 only (in-wave DS ordering suffices).
  if (lane == 0) {
    const float ssum = abuf[2 * Lb - 1] + abuf[2 * Lb];
    const float ll = (log2f(ssum) + log2C) * LN2;
    float nll = -ll;
    if (!(nll < 1e29f)) nll = 0.f;                 // zero_infinity (also catches inf/nan)
    atomicAdd(out, nll / ((float)(Lb > 0 ? Lb : 1) * (float)B));
  }
}

// ---------------------------------------------------------------------------
extern "C" void kernel_launch(void* const* d_in, const int* in_sizes, int n_in,
                              void* d_out, int out_size, void* d_ws, size_t ws_size,
                              hipStream_t stream) {
  const float* x      = (const float*)d_in[0];
  const float* W      = (const float*)d_in[1];
  const float* bias   = (const float*)d_in[2];
  const int*  target  = (const int*)d_in[3];
  const int*  ilen    = (const int*)d_in[4];
  const int*  tlen    = (const int*)d_in[5];

  const int B = in_sizes[4];
  const int V = in_sizes[2];
  const int D = in_sizes[1] / V;
  const int T = in_sizes[0] / (B * D);
  const int L = in_sizes[3] / B;
  const int M = B * T;

  char* ws = (char*)d_ws;
  const size_t xb_bytes = (size_t)M * D * 2;
  const size_t wt_bytes = (size_t)V * D * 2;
  uint16_t* xb = (uint16_t*)ws;
  uint16_t* Wt = (uint16_t*)(ws + xb_bytes);
  uint16_t* logits = (uint16_t*)(ws + xb_bytes + wt_bytes);
  const size_t log_bytes = (size_t)M * V * 2;

  const size_t pext_bytes = (size_t)(M + PEXT_PAD_ROWS) * PROW * 4;
  float* pext;
  if (pext_bytes <= xb_bytes + wt_bytes) {
    pext = (float*)ws;                 // overlay dead xb/Wt region after GEMM
  } else {
    pext = (float*)(ws + xb_bytes + wt_bytes + log_bytes);
  }

  const long long nx = (long long)M * D;
  const int nconv = (int)((nx / 8 + 255) / 256);
  const int ntrans = (V / 32) * (D / 32);
  k_prep<<<nconv + ntrans, 256, 0, stream>>>(x, xb, nx, W, Wt, D, V, (float*)d_out, nconv);
  k_gemm<<<(M / 128) * (V / 128), 256, 0, stream>>>(xb, Wt, bias, logits, M, V, D);
  k_softmax_gather<<<M / 4, 256, 0, stream>>>(logits, target, tlen, pext, T, V, L);
  k_ctc<<<B, 64 * (1 + NPROD), 0, stream>>>(pext, target, ilen, tlen, (float*)d_out, T, L);
}

// Round 12
// 155.236 us; speedup vs baseline: 1.1740x; 1.0066x over previous
//
#include <hip/hip_runtime.h>
#include <cstdint>

// ---------------------------------------------------------------------------
// CTC loss pipeline:
//   k_prep : x fp32->bf16, W[D,V] -> Wt[V,D] bf16, zero d_out
//   k_gemm : m97-structure bf16 MFMA GEMM, BK=64, 1-D grid with chunked-XCD
//            swizzle (n-major)
//   k_softmax_gather : row lse + ext-label exp-gather -> pext rows of 256
//            floats (s=0..255). State 256 (blank) == prow[0], no sidecar.
//   k_ctc  : R8's PASSING producer/consumer v2 (NPROD=6, CROWS=8, NSLOT=4)
//            with ONE reorder: publish is drained (lgkmcnt(0)) BEFORE the
//            reload is issued. R8 placed the wait AFTER the reload; if the
//            producer loads are flat_ (generic-pointer codegen) they count in
//            lgkmcnt too, so R8's wait serialized one full HBM round-trip
//            (~900cy) into every barrier-paced publish — matching the
//            unexplained ~1050cy/phase. Reordered, the wait covers only the
//            8 ds_writes; the reload stays in flight across barriers and is
//            consumed 6 phases later (counters long retired). WAR on the P
//            registers is closed by the same wait. v3 (R9/R10, deterministic
//            absmax 5.25) is abandoned per two-strike discipline.
// ---------------------------------------------------------------------------

#define PROW 256                      // pext row: 256 floats = 1 KiB
#define PEXT_PAD_ROWS 64              // prefetch overrun pad (loaded, never consumed)
#define NPROD 6                       // producer waves
#define NSLOT 4                       // LDS ring slots (8 KiB each)
#define L2E 1.4426950408889634f
#define LN2 0.6931471805599453f

typedef short v8s __attribute__((ext_vector_type(8)));
typedef float v4f __attribute__((ext_vector_type(4)));

__device__ __forceinline__ uint32_t f2bf_bits(float f) {
  uint32_t u = __float_as_uint(f);
  return (u + 0x7FFFu + ((u >> 16) & 1u)) >> 16;   // RNE
}
__device__ __forceinline__ float bf2f(uint32_t h) { return __uint_as_float(h << 16); }

// ---------------- k_prep: x fp32->bf16, W transpose->bf16, zero d_out ----------------
__global__ void k_prep(const float* __restrict__ x, uint16_t* __restrict__ xb, long long n,
                       const float* __restrict__ W, uint16_t* __restrict__ Wt, int D, int V,
                       float* __restrict__ out, int nconv) {
  if (blockIdx.x == 0 && threadIdx.x == 0) out[0] = 0.f;   // zero the atomic target
  if ((int)blockIdx.x < nconv) {
    long long i = ((long long)blockIdx.x * blockDim.x + threadIdx.x) * 8;
    if (i >= n) return;
    float4 a = *(const float4*)(x + i);
    float4 b = *(const float4*)(x + i + 4);
    uint4 o;
    o.x = f2bf_bits(a.x) | (f2bf_bits(a.y) << 16);
    o.y = f2bf_bits(a.z) | (f2bf_bits(a.w) << 16);
    o.z = f2bf_bits(b.x) | (f2bf_bits(b.y) << 16);
    o.w = f2bf_bits(b.z) | (f2bf_bits(b.w) << 16);
    *(uint4*)(xb + i) = o;
  } else {
    __shared__ float tile[32][33];
    const int bid2 = blockIdx.x - nconv;
    const int n0 = (bid2 % (V / 32)) * 32, k0 = (bid2 / (V / 32)) * 32;
    const int tx = threadIdx.x & 31, ty = threadIdx.x >> 5;   // (32,8)
    #pragma unroll
    for (int i = 0; i < 32; i += 8)
      tile[ty + i][tx] = W[(size_t)(k0 + ty + i) * V + n0 + tx];
    __syncthreads();
    #pragma unroll
    for (int i = 0; i < 32; i += 8)
      Wt[(size_t)(n0 + ty + i) * D + k0 + tx] = (uint16_t)f2bf_bits(tile[tx][ty + i]);
  }
}

// ---------------- k_gemm: m97 structure, BK=64, bf16 out, 1-D swizzled grid ----------------
__global__ __launch_bounds__(256) void k_gemm(const uint16_t* __restrict__ A,
                                              const uint16_t* __restrict__ Bt,
                                              const float* __restrict__ bias,
                                              uint16_t* __restrict__ C, int M, int N, int K) {
  __shared__ uint16_t As[2][128 * 32];   // [k-half][row*32 + k]  (64B rows)
  __shared__ uint16_t Bs[2][128 * 32];
  const int tid = threadIdx.x, lane = tid & 63, wave = tid >> 6;
  int d = blockIdx.x;
  const int nwg = gridDim.x;
  if ((nwg & 7) == 0) d = (d & 7) * (nwg >> 3) + (d >> 3);
  const int ntl = N >> 7;                       // N-tiles (n-major: fastest)
  const int m0 = (d / ntl) * 128, n0 = (d % ntl) * 128;
  const int wm = wave & 1, wn = wave >> 1;
  const int frow = lane & 15, kb = lane >> 4;
  const int lr = lane >> 2, kc = lane & 3;
  v4f acc[4][4] = {};

  for (int k0 = 0; k0 < K; k0 += 64) {
    __syncthreads();
    #pragma unroll
    for (int t = 0; t < 2; t++)
      #pragma unroll
      for (int i = 0; i < 2; i++) {
        const int r = (wave * 2 + i) * 16 + lr;
        const uint16_t* ga = A + (size_t)(m0 + r) * K + k0 + t * 32 + kc * 8;
        const uint16_t* gb = Bt + (size_t)(n0 + r) * K + k0 + t * 32 + kc * 8;
        __builtin_amdgcn_global_load_lds(
            (const __attribute__((address_space(1))) void*)ga,
            (__attribute__((address_space(3))) void*)(&As[t][0] + (wave * 2 + i) * 512 + lane * 8), 16, 0, 0);
        __builtin_amdgcn_global_load_lds(
            (const __attribute__((address_space(1))) void*)gb,
            (__attribute__((address_space(3))) void*)(&Bs[t][0] + (wave * 2 + i) * 512 + lane * 8), 16, 0, 0);
      }
    __syncthreads();

    #pragma unroll
    for (int t = 0; t < 2; t++) {
      v8s af[4], bf[4];
      #pragma unroll
      for (int i = 0; i < 4; i++)
        af[i] = *(const v8s*)(&As[t][0] + (wm * 64 + i * 16 + frow) * 32 + kb * 8);
      #pragma unroll
      for (int j = 0; j < 4; j++)
        bf[j] = *(const v8s*)(&Bs[t][0] + (wn * 64 + j * 16 + frow) * 32 + kb * 8);
      #pragma unroll
      for (int i = 0; i < 4; i++)
        #pragma unroll
        for (int j = 0; j < 4; j++)
          acc[i][j] = __builtin_amdgcn_mfma_f32_16x16x32_bf16(af[i], bf[j], acc[i][j], 0, 0, 0);
    }
  }

  const int crow = (lane >> 4) * 4, ccol = lane & 15;
  #pragma unroll
  for (int j = 0; j < 4; j++) {
    const int n = n0 + wn * 64 + j * 16 + ccol;
    const float bv = bias[n];
    #pragma unroll
    for (int i = 0; i < 4; i++) {
      const int mb = m0 + wm * 64 + i * 16 + crow;
      #pragma unroll
      for (int r2 = 0; r2 < 4; r2++)
        C[(size_t)(mb + r2) * N + n] = (uint16_t)f2bf_bits(acc[i][j][r2] + bv);
    }
  }
}

// ---------------- k_softmax_gather: row lse + gather (linear domain) ----------------
__global__ void k_softmax_gather(const uint16_t* __restrict__ logits, const int* __restrict__ target,
                                 const int* __restrict__ tlen, float* __restrict__ pext,
                                 int T, int V, int L) {
  const int row = blockIdx.x * 4 + (threadIdx.x >> 6);   // one wave per row
  const int lane = threadIdx.x & 63;
  const uint16_t* lrow = logits + (size_t)row * V;

  float xs[16];
  int cnt = 0;
  float mx = -INFINITY;
  for (int base = 0; base < V; base += 256) {
    const int idx = base + lane * 4;
    uint2 u = *(const uint2*)(lrow + idx);
    float4 v;
    v.x = bf2f(u.x & 0xFFFFu); v.y = bf2f(u.x >> 16);
    v.z = bf2f(u.y & 0xFFFFu); v.w = bf2f(u.y >> 16);
    xs[cnt] = v.x; xs[cnt + 1] = v.y; xs[cnt + 2] = v.z; xs[cnt + 3] = v.w; cnt += 4;
    mx = fmaxf(mx, fmaxf(fmaxf(v.x, v.y), fmaxf(v.z, v.w)));
  }
  #pragma unroll
  for (int off = 32; off; off >>= 1) mx = fmaxf(mx, __shfl_xor(mx, off, 64));
  float sum = 0.f;
  #pragma unroll
  for (int q = 0; q < 16; q++) { if (q < cnt) sum += exp2f((xs[q] - mx) * L2E); }
  #pragma unroll
  for (int off = 32; off; off >>= 1) sum += __shfl_xor(sum, off, 64);
  const float lse2 = mx * L2E + log2f(sum);

  const int bidx = row / T;
  const int Lb = tlen[bidx];
  const int S = 2 * Lb + 1;
  float* prow = pext + (size_t)row * PROW;
  #pragma unroll
  for (int it = 0; it < PROW / 64; it++) {
    const int s = lane + it * 64;
    float p = 0.f;
    if (s < S) {
      const int lbl = (s & 1) ? target[bidx * L + ((s - 1) >> 1)] : 0;
      p = exp2f(bf2f(lrow[lbl]) * L2E - lse2);
    }
    prow[s] = p;
  }
}

// ---------------- k_ctc: producer/consumer v2 (R8-passing) + drain-then-reload ----------------
__device__ __forceinline__ float wave_shr1(float x) {   // lane l <- lane l-1, lane0 <- 0
  return __int_as_float(__builtin_amdgcn_update_dpp(0, __float_as_int(x), 0x138, 0xf, 0xf, true));
}
__device__ __forceinline__ float wave_max_nonneg(float x) {
  x = fmaxf(x, __int_as_float(__builtin_amdgcn_update_dpp(0, __float_as_int(x), 0x111, 0xf, 0xf, true)));
  x = fmaxf(x, __int_as_float(__builtin_amdgcn_update_dpp(0, __float_as_int(x), 0x112, 0xf, 0xf, true)));
  x = fmaxf(x, __int_as_float(__builtin_amdgcn_update_dpp(0, __float_as_int(x), 0x114, 0xf, 0xf, true)));
  x = fmaxf(x, __int_as_float(__builtin_amdgcn_update_dpp(0, __float_as_int(x), 0x118, 0xf, 0xf, true)));
  x = fmaxf(x, __int_as_float(__builtin_amdgcn_update_dpp(0, __float_as_int(x), 0x142, 0xf, 0xf, true)));
  x = fmaxf(x, __int_as_float(__builtin_amdgcn_update_dpp(0, __float_as_int(x), 0x143, 0xf, 0xf, true)));
  return __int_as_float(__builtin_amdgcn_readlane(__float_as_int(x), 63));
}

__global__ __launch_bounds__(448, 1) void k_ctc(const float* __restrict__ pext,
                                                const int* __restrict__ target,
                                                const int* __restrict__ ilen,
                                                const int* __restrict__ tlen,
                                                float* __restrict__ out, int T, int L) {
  __shared__ __attribute__((aligned(16))) float ring[NSLOT][8][PROW];   // 32 KiB
  __shared__ float abuf[257];

  const int b = blockIdx.x;
  const int tid = threadIdx.x;
  const int lane = tid & 63, wave = tid >> 6;
  const int B = gridDim.x;
  const int Tb = ilen[b];
  const int Lb = tlen[b];
  const int S = 2 * Lb + 1;
  const int* tg = target + b * L;
  const float* pb = pext + (size_t)b * T * PROW;
  // Phase structure: CT = (Tb-1)/8 + 1 phases; phases 0..CT-2 are full (8
  // steps), phase CT-1 is the tail. Every wave executes exactly CT+1
  // s_barriers (1 prologue + 1 per phase).
  const int CT = (Tb - 1) / 8 + 1;

  if (wave > 0) {
    // ---------------- producers (waves 1..NPROD) ----------------
    const int p = wave - 1;              // owns chunks c with c % NPROD == p
    float4 P0, P1, P2, P3, P4, P5, P6, P7;   // named regs: no spill (R5 lesson)

    #define LOADCHUNK(c) {                                                  \
      const float* s_ = pb + (size_t)(1 + 8 * (c)) * PROW + (lane << 2);    \
      P0 = *(const float4*)(s_);            P1 = *(const float4*)(s_ + PROW);     \
      P2 = *(const float4*)(s_ + 2 * PROW); P3 = *(const float4*)(s_ + 3 * PROW); \
      P4 = *(const float4*)(s_ + 4 * PROW); P5 = *(const float4*)(s_ + 5 * PROW); \
      P6 = *(const float4*)(s_ + 6 * PROW); P7 = *(const float4*)(s_ + 7 * PROW); }
    #define WRITECHUNK(c) {                                                 \
      const int sl_ = (c) & (NSLOT - 1);                                    \
      *(float4*)(&ring[sl_][0][lane << 2]) = P0; *(float4*)(&ring[sl_][1][lane << 2]) = P1; \
      *(float4*)(&ring[sl_][2][lane << 2]) = P2; *(float4*)(&ring[sl_][3][lane << 2]) = P3; \
      *(float4*)(&ring[sl_][4][lane << 2]) = P4; *(float4*)(&ring[sl_][5][lane << 2]) = P5; \
      *(float4*)(&ring[sl_][6][lane << 2]) = P6; *(float4*)(&ring[sl_][7][lane << 2]) = P7; }

    if (p < CT) LOADCHUNK(p);            // first owned chunk
    if (p == 0 && 0 < CT) {              // publish chunk 0 in the prologue
      WRITECHUNK(0);
      // Drain the publish FIRST (only ds_writes outstanding here), THEN issue
      // the reload so it is never covered by a critical-path lgkmcnt wait.
      asm volatile("s_waitcnt lgkmcnt(0)" ::: "memory");
      if (NPROD < CT) LOADCHUNK(NPROD);  // in flight across barriers
      __builtin_amdgcn_sched_barrier(0);
    }
    __builtin_amdgcn_s_barrier();        // prologue barrier

    for (int c = 0; c < CT; ++c) {
      const int cpub = c + 1;            // chunk consumed at phase c+1
      if (cpub < CT && (cpub % NPROD) == p) {
        WRITECHUNK(cpub);                // regs loaded NPROD phases ago
        // publish drained before regs are overwritten (closes the WAR) and
        // before the barrier (visibility); reload issued after -> its
        // vmcnt/lgkmcnt is retired long before its publish 6 phases later.
        asm volatile("s_waitcnt lgkmcnt(0)" ::: "memory");
        const int cn = cpub + NPROD;
        if (cn < CT) LOADCHUNK(cn);
        __builtin_amdgcn_sched_barrier(0);
      }
      __builtin_amdgcn_s_barrier();
    }
    return;
  }

  // ---------------- wave 0: consumer (bit-identical arithmetic to R4/R8) ----------------
  const int s1 = 4 * lane + 1, s3 = 4 * lane + 3;
  float sk1 = 0.f, sk3 = 0.f;
  if (s1 >= 3 && s1 < S) sk1 = (tg[(s1 - 1) >> 1] != tg[(s1 - 3) >> 1]) ? 1.f : 0.f;
  if (s3 >= 3 && s3 < S) sk3 = (tg[(s3 - 1) >> 1] != tg[(s3 - 3) >> 1]) ? 1.f : 0.f;

  const float4 p0 = *(const float4*)(pb + (lane << 2));
  float a0 = (lane == 0) ? p0.x : 0.f;
  float a1 = (lane == 0) ? p0.y : 0.f;
  float a2 = 0.f, a3 = 0.f, a4 = 0.f;
  float log2C = 0.f;

  // State 256 is even -> blank -> equals prow[0] (lane 0's P.x): readlane.
  #define CTC_STEP(PP) {                                                \
    const float pm3 = wave_shr1(a3);                                    \
    const float a255 = __int_as_float(__builtin_amdgcn_readlane(__float_as_int(a3), 63)); \
    const float p4v = __int_as_float(__builtin_amdgcn_readlane(__float_as_int((PP).x), 0)); \
    const float n0v = (a0 + pm3) * (PP).x;                              \
    const float n1v = (a1 + a0 + sk1 * pm3) * (PP).y;                   \
    const float n2v = (a2 + a1) * (PP).z;                               \
    const float n3v = (a3 + a2 + sk3 * a1) * (PP).w;                    \
    const float n4v = (a4 + a255) * p4v;                                \
    a0 = n0v; a1 = n1v; a2 = n2v; a3 = n3v; a4 = n4v; }

  #define RENORM {                                                      \
    float m = fmaxf(fmaxf(fmaxf(a0, a1), fmaxf(a2, a3)), a4);           \
    m = wave_max_nonneg(m);                                             \
    const int e = (int)((__float_as_uint(m) >> 23) & 255u) - 127;       \
    const float scale = __uint_as_float((uint32_t)(127 - e) << 23);     \
    a0 *= scale; a1 *= scale; a2 *= scale; a3 *= scale; a4 *= scale;    \
    log2C += (float)e; }

  __builtin_amdgcn_s_barrier();          // prologue barrier (chunk 0 published)

  for (int c = 0; c < CT; ++c) {
    const int slot = c & (NSLOT - 1);
    float4 P[8];
    #pragma unroll
    for (int k = 0; k < 8; ++k)
      P[k] = *(const float4*)(&ring[slot][k][lane << 2]);
    const int t0 = 1 + 8 * c;
    if (t0 + 8 <= Tb) {
      #pragma unroll
      for (int k = 0; k < 8; ++k) CTC_STEP(P[k]);
      RENORM;
    } else {
      #pragma unroll
      for (int k = 0; k < 8; ++k) { if (t0 + k < Tb) CTC_STEP(P[k]); }
      RENORM;
    }
    __builtin_amdgcn_s_barrier();
  }

  abuf[4 * lane + 0] = a0; abuf[4 * lane + 1] = a1;
  abuf[4 * lane + 2] = a2; abuf[4 * lane + 3] = a3;
  if (lane == 63) abuf[256] = a4;
  // abuf is written and read by wave 0 only (in-wave DS ordering suffices).
  if (lane == 0) {
    const float ssum = abuf[2 * Lb - 1] + abuf[2 * Lb];
    const float ll = (log2f(ssum) + log2C) * LN2;
    float nll = -ll;
    if (!(nll < 1e29f)) nll = 0.f;                 // zero_infinity (also catches inf/nan)
    atomicAdd(out, nll / ((float)(Lb > 0 ? Lb : 1) * (float)B));
  }
}

// ---------------------------------------------------------------------------
extern "C" void kernel_launch(void* const* d_in, const int* in_sizes, int n_in,
                              void* d_out, int out_size, void* d_ws, size_t ws_size,
                              hipStream_t stream) {
  const float* x      = (const float*)d_in[0];
  const float* W      = (const float*)d_in[1];
  const float* bias   = (const float*)d_in[2];
  const int*  target  = (const int*)d_in[3];
  const int*  ilen    = (const int*)d_in[4];
  const int*  tlen    = (const int*)d_in[5];

  const int B = in_sizes[4];
  const int V = in_sizes[2];
  const int D = in_sizes[1] / V;
  const int T = in_sizes[0] / (B * D);
  const int L = in_sizes[3] / B;
  const int M = B * T;

  char* ws = (char*)d_ws;
  const size_t xb_bytes = (size_t)M * D * 2;
  const size_t wt_bytes = (size_t)V * D * 2;
  uint16_t* xb = (uint16_t*)ws;
  uint16_t* Wt = (uint16_t*)(ws + xb_bytes);
  uint16_t* logits = (uint16_t*)(ws + xb_bytes + wt_bytes);
  const size_t log_bytes = (size_t)M * V * 2;

  const size_t pext_bytes = (size_t)(M + PEXT_PAD_ROWS) * PROW * 4;
  float* pext;
  if (pext_bytes <= xb_bytes + wt_bytes) {
    pext = (float*)ws;                 // overlay dead xb/Wt region after GEMM
  } else {
    pext = (float*)(ws + xb_bytes + wt_bytes + log_bytes);
  }

  const long long nx = (long long)M * D;
  const int nconv = (int)((nx / 8 + 255) / 256);
  const int ntrans = (V / 32) * (D / 32);
  k_prep<<<nconv + ntrans, 256, 0, stream>>>(x, xb, nx, W, Wt, D, V, (float*)d_out, nconv);
  k_gemm<<<(M / 128) * (V / 128), 256, 0, stream>>>(xb, Wt, bias, logits, M, V, D);
  k_softmax_gather<<<M / 4, 256, 0, stream>>>(logits, target, tlen, pext, T, V, L);
  k_ctc<<<B, 64 * (1 + NPROD), 0, stream>>>(pext, target, ilen, tlen, (float*)d_out, T, L);
}